// Round 3
// baseline (1048.217 us; speedup 1.0000x reference)
//
#include <hip/hip_runtime.h>

typedef unsigned short u16;
typedef unsigned int u32;
typedef short bf16x8 __attribute__((ext_vector_type(8)));
typedef float f32x4 __attribute__((ext_vector_type(4)));

__device__ __forceinline__ u16 f2b(float f) {
    union { float f; unsigned u; } x; x.f = f;
    unsigned r = x.u + 0x7fffu + ((x.u >> 16) & 1u);
    return (u16)(r >> 16);
}

// ---------------------------------------------------------------- prep kernels

__global__ void conv_adj(const float* __restrict__ adj, u16* __restrict__ adjB) {
    size_t i = ((size_t)blockIdx.x * 256 + threadIdx.x) * 4;
    if (i < 16777216u) {
        float4 v = *(const float4*)(adj + i);
        u16* o = adjB + i;
        o[0] = f2b(v.x); o[1] = f2b(v.y); o[2] = f2b(v.z); o[3] = f2b(v.w);
    }
}

__global__ void prep_weights(const float* __restrict__ gw0, const float* __restrict__ gw1,
                             const float* __restrict__ gw2, const float* __restrict__ gw3,
                             u16* __restrict__ gw0T, u16* __restrict__ gw1T,
                             u16* __restrict__ gw2T, u16* __restrict__ gw3T) {
    int i = blockIdx.x * 256 + threadIdx.x;
    if (i < 128 * 320) {                 // gw0T [128][320], K pad 300->320
        int n = i / 320, k = i % 320;
        gw0T[i] = (k < 300) ? f2b(gw0[k * 128 + n]) : (u16)0;
    }
    if (i < 128 * 128) {                 // [128][128]
        int n = i >> 7, k = i & 127;
        gw1T[i] = f2b(gw1[k * 128 + n]);
        gw2T[i] = f2b(gw2[k * 128 + n]);
        gw3T[i] = (n < 50) ? f2b(gw3[k * 50 + n]) : (u16)0;   // N pad 50->128
    }
}

// ---------------------------------------------------------------- action MLP

__global__ void action_mlp(const float* __restrict__ mask,
                           const float* __restrict__ aw1, const float* __restrict__ ab1,
                           const float* __restrict__ aw2, const float* __restrict__ ab2,
                           const float* __restrict__ aw3, const float* __restrict__ ab3,
                           u16* __restrict__ aEmbB) {
    __shared__ float sm[50], sh1[200], sh2[100];
    int b = blockIdx.x, t = threadIdx.x;
    if (t < 50) sm[t] = mask[b * 50 + t];
    __syncthreads();
    if (t < 200) {
        float s = ab1[t];
        for (int k = 0; k < 50; ++k) s = fmaf(sm[k], aw1[k * 200 + t], s);
        sh1[t] = fmaxf(s, 0.f);
    }
    __syncthreads();
    if (t < 100) {
        float s = ab2[t];
        for (int k = 0; k < 200; ++k) s = fmaf(sh1[k], aw2[k * 100 + t], s);
        sh2[t] = fmaxf(s, 0.f);
    }
    __syncthreads();
    if (t < 100) {
        float s = ab3[t];
        for (int k = 0; k < 100; ++k) s = fmaf(sh2[k], aw3[k * 100 + t], s);
        aEmbB[b * 100 + t] = f2b(s);
    }
}

// ------------------------------------------------- node features (nerf + pos MLP + concat)
// 4 threads per node (wave w = final-layer channel slice w*25..w*25+24).
// h1/h2 recomputed per slice (redundant but removes cross-thread deps).
// Block: 256 threads = 64 nodes. LDS stage st[64][330 u16] (stride 165 dw = 5 mod 32
// -> 2-lane/bank, free), then full-line coalesced drain (contiguous 40 KB per block).

__global__ __launch_bounds__(256)
void node_features(const float* __restrict__ mesh, const int* __restrict__ midx,
                   const float* __restrict__ emb,
                   const float* __restrict__ pw1, const float* __restrict__ pb1,
                   const float* __restrict__ pw2, const float* __restrict__ pb2,
                   const float* __restrict__ pw3, const float* __restrict__ pb3,
                   const u16* __restrict__ aEmbB, u16* __restrict__ X0) {
    __shared__ u16 st[64 * 330];
    const int tid = threadIdx.x;
    const int w = tid >> 6;               // wave = channel slice 0..3
    const int n = tid & 63;               // node within block
    const size_t r = (size_t)blockIdx.x * 64 + n;
    const int bb = blockIdx.x >> 6;       // batch (64 blocks per batch of 4096 nodes)

    float m3[3];
    m3[0] = mesh[3 * r]; m3[1] = mesh[3 * r + 1]; m3[2] = mesh[3 * r + 2];

    // layer 1: 63 -> 25 (inputs generated on the fly; no in[63] array)
    float h1[25];
#pragma unroll
    for (int j = 0; j < 25; ++j) h1[j] = pb1[j];
#pragma unroll
    for (int d = 0; d < 3; ++d) {
#pragma unroll
        for (int i = 0; i < 10; ++i) {
            float fq = (i == 0) ? 3.14159265358979f : 6.28318530717959f * (float)i;
            float s, c;
            __sincosf(m3[d] * fq, &s, &c);
            int ks = i * 6 + d, kc = i * 6 + 3 + d;
#pragma unroll
            for (int j = 0; j < 25; ++j) h1[j] = fmaf(s, pw1[ks * 25 + j], h1[j]);
#pragma unroll
            for (int j = 0; j < 25; ++j) h1[j] = fmaf(c, pw1[kc * 25 + j], h1[j]);
        }
#pragma unroll
        for (int j = 0; j < 25; ++j) h1[j] = fmaf(m3[d], pw1[(60 + d) * 25 + j], h1[j]);
    }
#pragma unroll
    for (int j = 0; j < 25; ++j) h1[j] = fmaxf(h1[j], 0.f);

    // layer 2: 25 -> 50
    float h2[50];
#pragma unroll
    for (int j = 0; j < 50; ++j) h2[j] = pb2[j];
#pragma unroll
    for (int k = 0; k < 25; ++k) {
        float x = h1[k];
#pragma unroll
        for (int j = 0; j < 50; ++j) h2[j] = fmaf(x, pw2[k * 50 + j], h2[j]);
    }
#pragma unroll
    for (int j = 0; j < 50; ++j) h2[j] = fmaxf(h2[j], 0.f);

    // layer 3 slice: 50 -> 25 (channels w*25 .. w*25+24)
    float pc[25];
#pragma unroll
    for (int j = 0; j < 25; ++j) pc[j] = pb3[w * 25 + j];
#pragma unroll
    for (int k = 0; k < 50; ++k) {
        float x = h2[k];
#pragma unroll
        for (int j = 0; j < 25; ++j) pc[j] = fmaf(x, pw3[k * 100 + w * 25 + j], pc[j]);
    }

    const int mi = midx[r];
    const float* erow = emb + mi * 100;

    // fill LDS: each wave covers its 25-channel slice of each 100-wide section
    u16* row = st + n * 330;
#pragma unroll
    for (int j = 0; j < 25; ++j) row[w * 25 + j] = aEmbB[bb * 100 + w * 25 + j];
#pragma unroll
    for (int j = 0; j < 25; ++j) row[100 + w * 25 + j] = f2b(pc[j]);
#pragma unroll
    for (int j = 0; j < 25; ++j) row[200 + w * 25 + j] = f2b(erow[w * 25 + j]);
#pragma unroll
    for (int j = 0; j < 5; ++j)  row[300 + w * 5 + j] = 0;
    __syncthreads();

    // drain: block region is contiguous 64*640 B; lane-consecutive dwords
    u32* gout = (u32*)X0 + (size_t)blockIdx.x * 64 * 160;
#pragma unroll
    for (int it = 0; it < 40; ++it) {
        int f = tid + it * 256;           // dword index 0..10239
        int rr = f / 160, cc = f - rr * 160;
        gout[f] = *(const u32*)((const char*)st + rr * 660 + cc * 4);
    }
}

// ---------------------------------------------------------------- MFMA GEMM (C = A * B^T)
// A [M x kd] bf16 row-major, B [N x kd] bf16 row-major.
// 128x128 tile, 4 waves 2x2, 16x16x32 frags.
// EPI 0: feature GEMM layers 0-2 -> FT (c<42, transposed) + Xnext (relu, c>=42)
// EPI 1: feature GEMM layer 3    -> FT (c<50, transposed)
template <int EPI>
__launch_bounds__(256)
__global__ void gemm_bt(const u16* __restrict__ A, const u16* __restrict__ B, int kd,
                        u16* __restrict__ outX, u16* __restrict__ outFT) {
    __shared__ u16 As[128 * 32];
    __shared__ u16 Bs[128 * 32];
    const int tid = threadIdx.x;
    const int wave = tid >> 6, lane = tid & 63;
    const int wr = wave >> 1, wc = wave & 1;
    const int tM = blockIdx.x * 128, tN = blockIdx.y * 128;
    const int lrow = lane & 15, kg = lane >> 4;

    f32x4 acc[4][4];
#pragma unroll
    for (int m = 0; m < 4; ++m)
#pragma unroll
        for (int n = 0; n < 4; ++n) acc[m][n] = (f32x4){0.f, 0.f, 0.f, 0.f};

    for (int kt = 0; kt < kd; kt += 32) {
        __syncthreads();
#pragma unroll
        for (int i = 0; i < 2; ++i) {
            int loff = i * 4096 + tid * 16;
            int row = loff >> 6;
            int colb = loff & 63;
            const u16* ga = A + (size_t)(tM + row) * kd + kt + (colb >> 1);
            const u16* gb = B + (size_t)(tN + row) * kd + kt + (colb >> 1);
            int lbase = i * 4096 + wave * 1024;
            __builtin_amdgcn_global_load_lds(
                (__attribute__((address_space(1))) void*)ga,
                (__attribute__((address_space(3))) void*)((char*)(&As[0]) + lbase), 16, 0, 0);
            __builtin_amdgcn_global_load_lds(
                (__attribute__((address_space(1))) void*)gb,
                (__attribute__((address_space(3))) void*)((char*)(&Bs[0]) + lbase), 16, 0, 0);
        }
        __syncthreads();
        bf16x8 af[4], bfr[4];
#pragma unroll
        for (int m = 0; m < 4; ++m)
            af[m] = *(const bf16x8*)&As[(wr * 64 + m * 16 + lrow) * 32 + kg * 8];
#pragma unroll
        for (int n = 0; n < 4; ++n)
            bfr[n] = *(const bf16x8*)&Bs[(wc * 64 + n * 16 + lrow) * 32 + kg * 8];
#pragma unroll
        for (int m = 0; m < 4; ++m)
#pragma unroll
            for (int n = 0; n < 4; ++n)
                acc[m][n] = __builtin_amdgcn_mfma_f32_16x16x32_bf16(af[m], bfr[n], acc[m][n], 0, 0, 0);
    }

    const int rbase = tM + wr * 64 + ((lane >> 4) << 2);
    const int cbase = tN + wc * 64 + (lane & 15);
#pragma unroll
    for (int m = 0; m < 4; ++m) {
#pragma unroll
        for (int n = 0; n < 4; ++n) {
#pragma unroll
            for (int j = 0; j < 4; ++j) {
                int r = rbase + m * 16 + j;
                int c = cbase + n * 16;
                float v = acc[m][n][j];
                if (EPI == 0) {
                    if (c < 42) {
                        int b = r >> 12, node = r & 4095;
                        outFT[(size_t)(b * 42 + c) * 4096 + node] = f2b(v);
                    } else {
                        outX[(size_t)r * 128 + c] = f2b(fmaxf(v, 0.f));
                    }
                } else {
                    if (c < 50) {
                        int b = r >> 12, node = r & 4095;
                        outFT[(size_t)(b * 50 + c) * 4096 + node] = f2b(v);
                    }
                }
            }
        }
    }
}

// ---------------------------------------------------------------- adj GEMM, split-K x4
// C[c][r] += adj-tile * FT-tile over K slice [z*1024, z*1024+1024), f32 atomics.
__launch_bounds__(256)
__global__ void gemm_adj_splitk(const u16* __restrict__ A, const u16* __restrict__ B,
                                float* __restrict__ C, int ncol) {
    __shared__ u16 As[128 * 32];
    __shared__ u16 Bs[128 * 32];
    const int tid = threadIdx.x;
    const int wave = tid >> 6, lane = tid & 63;
    const int wr = wave >> 1, wc = wave & 1;
    const int tM = blockIdx.x * 128, tN = blockIdx.y * 128;
    const int k0 = blockIdx.z * 1024;
    const int lrow = lane & 15, kg = lane >> 4;
    const int kd = 4096;

    f32x4 acc[4][4];
#pragma unroll
    for (int m = 0; m < 4; ++m)
#pragma unroll
        for (int n = 0; n < 4; ++n) acc[m][n] = (f32x4){0.f, 0.f, 0.f, 0.f};

    for (int kt = k0; kt < k0 + 1024; kt += 32) {
        __syncthreads();
#pragma unroll
        for (int i = 0; i < 2; ++i) {
            int loff = i * 4096 + tid * 16;
            int row = loff >> 6;
            int colb = loff & 63;
            const u16* ga = A + (size_t)(tM + row) * kd + kt + (colb >> 1);
            const u16* gb = B + (size_t)(tN + row) * kd + kt + (colb >> 1);
            int lbase = i * 4096 + wave * 1024;
            __builtin_amdgcn_global_load_lds(
                (__attribute__((address_space(1))) void*)ga,
                (__attribute__((address_space(3))) void*)((char*)(&As[0]) + lbase), 16, 0, 0);
            __builtin_amdgcn_global_load_lds(
                (__attribute__((address_space(1))) void*)gb,
                (__attribute__((address_space(3))) void*)((char*)(&Bs[0]) + lbase), 16, 0, 0);
        }
        __syncthreads();
        bf16x8 af[4], bfr[4];
#pragma unroll
        for (int m = 0; m < 4; ++m)
            af[m] = *(const bf16x8*)&As[(wr * 64 + m * 16 + lrow) * 32 + kg * 8];
#pragma unroll
        for (int n = 0; n < 4; ++n)
            bfr[n] = *(const bf16x8*)&Bs[(wc * 64 + n * 16 + lrow) * 32 + kg * 8];
#pragma unroll
        for (int m = 0; m < 4; ++m)
#pragma unroll
            for (int n = 0; n < 4; ++n)
                acc[m][n] = __builtin_amdgcn_mfma_f32_16x16x32_bf16(af[m], bfr[n], acc[m][n], 0, 0, 0);
    }

    const int rbase = tM + wr * 64 + ((lane >> 4) << 2);
    const int cbase = tN + wc * 64 + (lane & 15);
#pragma unroll
    for (int m = 0; m < 4; ++m) {
#pragma unroll
        for (int n = 0; n < 4; ++n) {
            int c = cbase + n * 16;
            if (c < ncol) {
#pragma unroll
                for (int j = 0; j < 4; ++j) {
                    int r = rbase + m * 16 + j;
                    unsafeAtomicAdd(&C[(size_t)c * 4096 + r], acc[m][n][j]);
                }
            }
        }
    }
}

// ---------------------------------------------------------------- epilogue: bias+relu -> X cols 0..41

__global__ __launch_bounds__(256)
void epi_bias_relu(const float* __restrict__ AGGP, const float* __restrict__ bias,
                   u16* __restrict__ X) {
    int node = blockIdx.x * 256 + threadIdx.x;     // 0..65535
    int b = node >> 12, nn = node & 4095;
    u32 pk[21];
#pragma unroll
    for (int p = 0; p < 21; ++p) {
        float v0 = fmaxf(AGGP[(size_t)(b * 42 + 2 * p) * 4096 + nn] + bias[2 * p], 0.f);
        float v1 = fmaxf(AGGP[(size_t)(b * 42 + 2 * p + 1) * 4096 + nn] + bias[2 * p + 1], 0.f);
        pk[p] = (u32)f2b(v0) | ((u32)f2b(v1) << 16);
    }
    u32* xr = (u32*)(X + (size_t)node * 128);
#pragma unroll
    for (int p = 0; p < 21; ++p) xr[p] = pk[p];
}

// ---------------------------------------------------------------- final max over nodes (+bias)

__global__ void max_reduce(const float* __restrict__ AGG, const float* __restrict__ bias,
                           float* __restrict__ out) {
    __shared__ float sred[256];
    int c = blockIdx.x;                       // 0..799 == b*50+l
    const float* row = AGG + (size_t)c * 4096;
    float m = -1e30f;
    for (int i = threadIdx.x; i < 4096; i += 256) m = fmaxf(m, row[i]);
    sred[threadIdx.x] = m;
    __syncthreads();
    for (int s = 128; s > 0; s >>= 1) {
        if (threadIdx.x < s) sred[threadIdx.x] = fmaxf(sred[threadIdx.x], sred[threadIdx.x + s]);
        __syncthreads();
    }
    if (threadIdx.x == 0) out[c] = sred[0] + bias[c % 50];
}

// ---------------------------------------------------------------- launch

extern "C" void kernel_launch(void* const* d_in, const int* in_sizes, int n_in,
                              void* d_out, int out_size, void* d_ws, size_t ws_size,
                              hipStream_t stream) {
    const float* mask = (const float*)d_in[0];
    const float* mesh = (const float*)d_in[1];
    const int*   midx = (const int*)d_in[2];
    const float* adj  = (const float*)d_in[3];
    const float* aw1 = (const float*)d_in[4],  *ab1 = (const float*)d_in[5];
    const float* aw2 = (const float*)d_in[6],  *ab2 = (const float*)d_in[7];
    const float* aw3 = (const float*)d_in[8],  *ab3 = (const float*)d_in[9];
    const float* pw1 = (const float*)d_in[10], *pb1 = (const float*)d_in[11];
    const float* pw2 = (const float*)d_in[12], *pb2 = (const float*)d_in[13];
    const float* pw3 = (const float*)d_in[14], *pb3 = (const float*)d_in[15];
    const float* emb = (const float*)d_in[16];
    const float* gw0 = (const float*)d_in[17], *gb0 = (const float*)d_in[18];
    const float* gw1 = (const float*)d_in[19], *gb1 = (const float*)d_in[20];
    const float* gw2 = (const float*)d_in[21], *gb2 = (const float*)d_in[22];
    const float* gw3 = (const float*)d_in[23], *gb3 = (const float*)d_in[24];
    float* out = (float*)d_out;

    char* w = (char*)d_ws;
    u16*   adjB  = (u16*)(w);                    // 33,554,432
    u16*   X0    = (u16*)(w + 33554432);         // 41,943,040
    // overlays on X0 (X0 dead after FGEMM layer 0):
    float* AGGP1 = (float*)(w + 33554432);       // 11,010,048
    float* AGGP2 = (float*)(w + 44564480);       // 11,010,048
    float* AGG3  = (float*)(w + 55574528);       // 13,107,200 (ends 68,681,728)
    u16*   X1    = (u16*)(w + 75497472);         // 16,777,216
    u16*   X2    = (u16*)(w + 92274688);         // 16,777,216
    float* AGGP0 = (float*)(w + 92274688);       // overlay on X2 (dead until epi0 done)
    u16*   FT    = (u16*)(w + 109051904);        // 7,340,032
    u16*   gw0T  = (u16*)(w + 116391936);
    u16*   gw1T  = (u16*)(w + 116473856);
    u16*   gw2T  = (u16*)(w + 116506624);
    u16*   gw3T  = (u16*)(w + 116539392);
    u16*   aEmbB = (u16*)(w + 116572160);

    // zero FT pad rows + AGGP0 (X2-overlay, consumed before X2 is written)
    hipMemsetAsync(FT + (size_t)672 * 4096, 0, (size_t)(896 - 672) * 4096 * 2, stream);
    hipMemsetAsync(AGGP0, 0, (size_t)672 * 4096 * 4, stream);

    prep_weights<<<dim3(160), dim3(256), 0, stream>>>(gw0, gw1, gw2, gw3, gw0T, gw1T, gw2T, gw3T);
    conv_adj<<<dim3(16384), dim3(256), 0, stream>>>(adj, adjB);
    action_mlp<<<dim3(16), dim3(256), 0, stream>>>(mask, aw1, ab1, aw2, ab2, aw3, ab3, aEmbB);
    node_features<<<dim3(1024), dim3(256), 0, stream>>>(mesh, midx, emb, pw1, pb1, pw2, pb2,
                                                        pw3, pb3, aEmbB, X0);
    // layer 0
    gemm_bt<0><<<dim3(512, 1), dim3(256), 0, stream>>>(X0, gw0T, 320, X1, FT);
    // X0 now dead: zero the overlay region (AGGP1, AGGP2, AGG3)
    hipMemsetAsync(AGGP1, 0, 35127296, stream);
    gemm_adj_splitk<<<dim3(32, 6, 4), dim3(256), 0, stream>>>(adjB, FT, AGGP0, 672);
    epi_bias_relu<<<dim3(256), dim3(256), 0, stream>>>(AGGP0, gb0, X1);
    // layer 1
    gemm_bt<0><<<dim3(512, 1), dim3(256), 0, stream>>>(X1, gw1T, 128, X2, FT);
    gemm_adj_splitk<<<dim3(32, 6, 4), dim3(256), 0, stream>>>(adjB, FT, AGGP1, 672);
    epi_bias_relu<<<dim3(256), dim3(256), 0, stream>>>(AGGP1, gb1, X2);
    // layer 2
    gemm_bt<0><<<dim3(512, 1), dim3(256), 0, stream>>>(X2, gw2T, 128, X1, FT);
    gemm_adj_splitk<<<dim3(32, 6, 4), dim3(256), 0, stream>>>(adjB, FT, AGGP2, 672);
    epi_bias_relu<<<dim3(256), dim3(256), 0, stream>>>(AGGP2, gb2, X1);
    // layer 3
    gemm_bt<1><<<dim3(512, 1), dim3(256), 0, stream>>>(X1, gw3T, 128, nullptr, FT);
    gemm_adj_splitk<<<dim3(32, 7, 4), dim3(256), 0, stream>>>(adjB, FT, AGG3, 800);

    max_reduce<<<dim3(800), dim3(256), 0, stream>>>(AGG3, gb3, out);
}

// Round 4
// 673.048 us; speedup vs baseline: 1.5574x; 1.5574x over previous
//
#include <hip/hip_runtime.h>

typedef unsigned short u16;
typedef unsigned int u32;
typedef short bf16x8 __attribute__((ext_vector_type(8)));
typedef float f32x4 __attribute__((ext_vector_type(4)));

__device__ __forceinline__ u16 f2b(float f) {
    union { float f; unsigned u; } x; x.f = f;
    unsigned r = x.u + 0x7fffu + ((x.u >> 16) & 1u);
    return (u16)(r >> 16);
}

// ---------------------------------------------------------------- prep kernels

__global__ void conv_adj(const float* __restrict__ adj, u16* __restrict__ adjB) {
    size_t i = ((size_t)blockIdx.x * 256 + threadIdx.x) * 4;
    if (i < 16777216u) {
        float4 v = *(const float4*)(adj + i);
        u16* o = adjB + i;
        o[0] = f2b(v.x); o[1] = f2b(v.y); o[2] = f2b(v.z); o[3] = f2b(v.w);
    }
}

__global__ void prep_weights(const float* __restrict__ gw0, const float* __restrict__ gw1,
                             const float* __restrict__ gw2, const float* __restrict__ gw3,
                             u16* __restrict__ gw0T, u16* __restrict__ gw1T,
                             u16* __restrict__ gw2T, u16* __restrict__ gw3T) {
    int i = blockIdx.x * 256 + threadIdx.x;
    if (i < 128 * 320) {                 // gw0T [128][320], K pad 300->320
        int n = i / 320, k = i % 320;
        gw0T[i] = (k < 300) ? f2b(gw0[k * 128 + n]) : (u16)0;
    }
    if (i < 128 * 128) {                 // [128][128]
        int n = i >> 7, k = i & 127;
        gw1T[i] = f2b(gw1[k * 128 + n]);
        gw2T[i] = f2b(gw2[k * 128 + n]);
        gw3T[i] = (n < 50) ? f2b(gw3[k * 50 + n]) : (u16)0;   // N pad 50->128
    }
}

// ---------------------------------------------------------------- action MLP

__global__ void action_mlp(const float* __restrict__ mask,
                           const float* __restrict__ aw1, const float* __restrict__ ab1,
                           const float* __restrict__ aw2, const float* __restrict__ ab2,
                           const float* __restrict__ aw3, const float* __restrict__ ab3,
                           u16* __restrict__ aEmbB) {
    __shared__ float sm[50], sh1[200], sh2[100];
    int b = blockIdx.x, t = threadIdx.x;
    if (t < 50) sm[t] = mask[b * 50 + t];
    __syncthreads();
    if (t < 200) {
        float s = ab1[t];
        for (int k = 0; k < 50; ++k) s = fmaf(sm[k], aw1[k * 200 + t], s);
        sh1[t] = fmaxf(s, 0.f);
    }
    __syncthreads();
    if (t < 100) {
        float s = ab2[t];
        for (int k = 0; k < 200; ++k) s = fmaf(sh1[k], aw2[k * 100 + t], s);
        sh2[t] = fmaxf(s, 0.f);
    }
    __syncthreads();
    if (t < 100) {
        float s = ab3[t];
        for (int k = 0; k < 100; ++k) s = fmaf(sh2[k], aw3[k * 100 + t], s);
        aEmbB[b * 100 + t] = f2b(s);
    }
}

// ------------------------------------------------- node features (nerf + pos MLP + concat)
// 4 threads per node (wave w = final-layer channel slice w*25..w*25+24).

__global__ __launch_bounds__(256)
void node_features(const float* __restrict__ mesh, const int* __restrict__ midx,
                   const float* __restrict__ emb,
                   const float* __restrict__ pw1, const float* __restrict__ pb1,
                   const float* __restrict__ pw2, const float* __restrict__ pb2,
                   const float* __restrict__ pw3, const float* __restrict__ pb3,
                   const u16* __restrict__ aEmbB, u16* __restrict__ X0) {
    __shared__ u16 st[64 * 330];
    const int tid = threadIdx.x;
    const int w = tid >> 6;               // wave = channel slice 0..3
    const int n = tid & 63;               // node within block
    const size_t r = (size_t)blockIdx.x * 64 + n;
    const int bb = blockIdx.x >> 6;       // batch

    float m3[3];
    m3[0] = mesh[3 * r]; m3[1] = mesh[3 * r + 1]; m3[2] = mesh[3 * r + 2];

    float h1[25];
#pragma unroll
    for (int j = 0; j < 25; ++j) h1[j] = pb1[j];
#pragma unroll
    for (int d = 0; d < 3; ++d) {
#pragma unroll
        for (int i = 0; i < 10; ++i) {
            float fq = (i == 0) ? 3.14159265358979f : 6.28318530717959f * (float)i;
            float s, c;
            __sincosf(m3[d] * fq, &s, &c);
            int ks = i * 6 + d, kc = i * 6 + 3 + d;
#pragma unroll
            for (int j = 0; j < 25; ++j) h1[j] = fmaf(s, pw1[ks * 25 + j], h1[j]);
#pragma unroll
            for (int j = 0; j < 25; ++j) h1[j] = fmaf(c, pw1[kc * 25 + j], h1[j]);
        }
#pragma unroll
        for (int j = 0; j < 25; ++j) h1[j] = fmaf(m3[d], pw1[(60 + d) * 25 + j], h1[j]);
    }
#pragma unroll
    for (int j = 0; j < 25; ++j) h1[j] = fmaxf(h1[j], 0.f);

    float h2[50];
#pragma unroll
    for (int j = 0; j < 50; ++j) h2[j] = pb2[j];
#pragma unroll
    for (int k = 0; k < 25; ++k) {
        float x = h1[k];
#pragma unroll
        for (int j = 0; j < 50; ++j) h2[j] = fmaf(x, pw2[k * 50 + j], h2[j]);
    }
#pragma unroll
    for (int j = 0; j < 50; ++j) h2[j] = fmaxf(h2[j], 0.f);

    float pc[25];
#pragma unroll
    for (int j = 0; j < 25; ++j) pc[j] = pb3[w * 25 + j];
#pragma unroll
    for (int k = 0; k < 50; ++k) {
        float x = h2[k];
#pragma unroll
        for (int j = 0; j < 25; ++j) pc[j] = fmaf(x, pw3[k * 100 + w * 25 + j], pc[j]);
    }

    const int mi = midx[r];
    const float* erow = emb + mi * 100;

    u16* row = st + n * 330;
#pragma unroll
    for (int j = 0; j < 25; ++j) row[w * 25 + j] = aEmbB[bb * 100 + w * 25 + j];
#pragma unroll
    for (int j = 0; j < 25; ++j) row[100 + w * 25 + j] = f2b(pc[j]);
#pragma unroll
    for (int j = 0; j < 25; ++j) row[200 + w * 25 + j] = f2b(erow[w * 25 + j]);
#pragma unroll
    for (int j = 0; j < 5; ++j)  row[300 + w * 5 + j] = 0;
    __syncthreads();

    u32* gout = (u32*)X0 + (size_t)blockIdx.x * 64 * 160;
#pragma unroll
    for (int it = 0; it < 40; ++it) {
        int f = tid + it * 256;
        int rr = f / 160, cc = f - rr * 160;
        gout[f] = *(const u32*)((const char*)st + rr * 660 + cc * 4);
    }
}

// ---------------------------------------------------------------- MFMA GEMM (C = A * B^T)
// A [M x kd] bf16 row-major, B [N x kd] bf16 row-major.
// 128x128 tile, 4 waves 2x2, 16x16x32 frags. LDS 16B-slot XOR swizzle:
// physical slot p = logical slot g ^ ((row>>1)&3); staging pre-swizzles the
// GLOBAL source (same 64B segment, coalescing preserved), LDS dest stays linear.
// EPI 0: feature GEMM layers 0-2 -> FT (c<42, transposed) + Xnext (relu, c>=42)
// EPI 1: feature GEMM layer 3    -> FT (c<50, transposed)
// EPI 2: adj GEMM layers 0-2     -> Xnext = relu(v + bias[l]), c = b*42+l < 672
// EPI 3: adj GEMM layer 3        -> AGG f32 = v + bias[l],     c = b*50+l < 800
template <int EPI>
__launch_bounds__(256)
__global__ void gemm_bt(const u16* __restrict__ A, const u16* __restrict__ B, int kd,
                        u16* __restrict__ outX, u16* __restrict__ outFT,
                        float* __restrict__ outF32, const float* __restrict__ bias) {
    __shared__ u16 As[128 * 32];
    __shared__ u16 Bs[128 * 32];
    const int tid = threadIdx.x;
    const int wave = tid >> 6, lane = tid & 63;
    const int wr = wave >> 1, wc = wave & 1;
    const int tM = blockIdx.x * 128, tN = blockIdx.y * 128;
    const int lrow = lane & 15, kg = lane >> 4;
    // swizzled element offset for staging (global source side)
    const int gsw = (((tid & 3) ^ ((tid >> 3) & 3)) << 3);
    // swizzled byte offset for fragment reads (LDS side)
    const int psw = ((kg ^ ((lrow >> 1) & 3)) << 4);

    f32x4 acc[4][4];
#pragma unroll
    for (int m = 0; m < 4; ++m)
#pragma unroll
        for (int n = 0; n < 4; ++n) acc[m][n] = (f32x4){0.f, 0.f, 0.f, 0.f};

    for (int kt = 0; kt < kd; kt += 32) {
        __syncthreads();
#pragma unroll
        for (int i = 0; i < 2; ++i) {
            int row = i * 64 + (tid >> 2);
            const u16* ga = A + (size_t)(tM + row) * kd + kt + gsw;
            const u16* gb = B + (size_t)(tN + row) * kd + kt + gsw;
            int lbase = i * 4096 + wave * 1024;  // wave-uniform LDS byte base, linear dest
            __builtin_amdgcn_global_load_lds(
                (__attribute__((address_space(1))) void*)ga,
                (__attribute__((address_space(3))) void*)((char*)(&As[0]) + lbase), 16, 0, 0);
            __builtin_amdgcn_global_load_lds(
                (__attribute__((address_space(1))) void*)gb,
                (__attribute__((address_space(3))) void*)((char*)(&Bs[0]) + lbase), 16, 0, 0);
        }
        __syncthreads();
        bf16x8 af[4], bfr[4];
#pragma unroll
        for (int m = 0; m < 4; ++m)
            af[m] = *(const bf16x8*)((const char*)As + (wr * 64 + m * 16 + lrow) * 64 + psw);
#pragma unroll
        for (int n = 0; n < 4; ++n)
            bfr[n] = *(const bf16x8*)((const char*)Bs + (wc * 64 + n * 16 + lrow) * 64 + psw);
#pragma unroll
        for (int m = 0; m < 4; ++m)
#pragma unroll
            for (int n = 0; n < 4; ++n)
                acc[m][n] = __builtin_amdgcn_mfma_f32_16x16x32_bf16(af[m], bfr[n], acc[m][n], 0, 0, 0);
    }

    const int rbase = tM + wr * 64 + ((lane >> 4) << 2);
    const int cbase = tN + wc * 64 + (lane & 15);
#pragma unroll
    for (int m = 0; m < 4; ++m) {
        int r0 = rbase + m * 16;                  // 4-aligned; j rows are r0..r0+3
#pragma unroll
        for (int n = 0; n < 4; ++n) {
            int c = cbase + n * 16;
            if (EPI == 0) {
                if (c < 42) {
                    int b = r0 >> 12, node = r0 & 4095;
                    u32 lo = (u32)f2b(acc[m][n][0]) | ((u32)f2b(acc[m][n][1]) << 16);
                    u32 hi = (u32)f2b(acc[m][n][2]) | ((u32)f2b(acc[m][n][3]) << 16);
                    u32* dst = (u32*)(outFT + (size_t)(b * 42 + c) * 4096 + node);
                    dst[0] = lo; dst[1] = hi;
                } else {
#pragma unroll
                    for (int j = 0; j < 4; ++j)
                        outX[(size_t)(r0 + j) * 128 + c] = f2b(fmaxf(acc[m][n][j], 0.f));
                }
            } else if (EPI == 1) {
                if (c < 50) {
                    int b = r0 >> 12, node = r0 & 4095;
                    u32 lo = (u32)f2b(acc[m][n][0]) | ((u32)f2b(acc[m][n][1]) << 16);
                    u32 hi = (u32)f2b(acc[m][n][2]) | ((u32)f2b(acc[m][n][3]) << 16);
                    u32* dst = (u32*)(outFT + (size_t)(b * 50 + c) * 4096 + node);
                    dst[0] = lo; dst[1] = hi;
                }
            } else if (EPI == 2) {
                if (c < 672) {
                    int b = c / 42, l = c - b * 42;
                    float bl = bias[l];
#pragma unroll
                    for (int j = 0; j < 4; ++j)
                        outX[(size_t)((b << 12) + r0 + j) * 128 + l] =
                            f2b(fmaxf(acc[m][n][j] + bl, 0.f));
                }
            } else {
                if (c < 800) {
                    int l = c % 50;
                    float bl = bias[l];
                    float4 v4 = {acc[m][n][0] + bl, acc[m][n][1] + bl,
                                 acc[m][n][2] + bl, acc[m][n][3] + bl};
                    *(float4*)(outF32 + (size_t)c * 4096 + r0) = v4;
                }
            }
        }
    }
}

// ---------------------------------------------------------------- final max over nodes

__global__ void max_reduce(const float* __restrict__ AGG, float* __restrict__ out) {
    __shared__ float sred[256];
    int c = blockIdx.x;                       // 0..799 == b*50+l
    const float* row = AGG + (size_t)c * 4096;
    float m = -1e30f;
    for (int i = threadIdx.x; i < 4096; i += 256) m = fmaxf(m, row[i]);
    sred[threadIdx.x] = m;
    __syncthreads();
    for (int s = 128; s > 0; s >>= 1) {
        if (threadIdx.x < s) sred[threadIdx.x] = fmaxf(sred[threadIdx.x], sred[threadIdx.x + s]);
        __syncthreads();
    }
    if (threadIdx.x == 0) out[c] = sred[0];
}

// ---------------------------------------------------------------- launch

extern "C" void kernel_launch(void* const* d_in, const int* in_sizes, int n_in,
                              void* d_out, int out_size, void* d_ws, size_t ws_size,
                              hipStream_t stream) {
    const float* mask = (const float*)d_in[0];
    const float* mesh = (const float*)d_in[1];
    const int*   midx = (const int*)d_in[2];
    const float* adj  = (const float*)d_in[3];
    const float* aw1 = (const float*)d_in[4],  *ab1 = (const float*)d_in[5];
    const float* aw2 = (const float*)d_in[6],  *ab2 = (const float*)d_in[7];
    const float* aw3 = (const float*)d_in[8],  *ab3 = (const float*)d_in[9];
    const float* pw1 = (const float*)d_in[10], *pb1 = (const float*)d_in[11];
    const float* pw2 = (const float*)d_in[12], *pb2 = (const float*)d_in[13];
    const float* pw3 = (const float*)d_in[14], *pb3 = (const float*)d_in[15];
    const float* emb = (const float*)d_in[16];
    const float* gw0 = (const float*)d_in[17], *gb0 = (const float*)d_in[18];
    const float* gw1 = (const float*)d_in[19], *gb1 = (const float*)d_in[20];
    const float* gw2 = (const float*)d_in[21], *gb2 = (const float*)d_in[22];
    const float* gw3 = (const float*)d_in[23], *gb3 = (const float*)d_in[24];
    float* out = (float*)d_out;

    char* w = (char*)d_ws;
    u16*   adjB  = (u16*)(w);                    // 33,554,432
    u16*   X0    = (u16*)(w + 33554432);         // 41,943,040
    float* AGG3  = (float*)(w + 33554432);       // overlay on X0 (dead by layer 3)
    u16*   X1    = (u16*)(w + 75497472);         // 16,777,216
    u16*   X2    = (u16*)(w + 92274688);         // 16,777,216
    u16*   FT    = (u16*)(w + 109051904);        // 896*4096*2 = 7,340,032
    u16*   gw0T  = (u16*)(w + 116391936);
    u16*   gw1T  = (u16*)(w + 116473856);
    u16*   gw2T  = (u16*)(w + 116506624);
    u16*   gw3T  = (u16*)(w + 116539392);
    u16*   aEmbB = (u16*)(w + 116572160);

    // zero FT pad rows (672..895) so padded GEMM columns read zeros
    hipMemsetAsync(FT + (size_t)672 * 4096, 0, (size_t)(896 - 672) * 4096 * 2, stream);

    prep_weights<<<dim3(160), dim3(256), 0, stream>>>(gw0, gw1, gw2, gw3, gw0T, gw1T, gw2T, gw3T);
    conv_adj<<<dim3(16384), dim3(256), 0, stream>>>(adj, adjB);
    action_mlp<<<dim3(16), dim3(256), 0, stream>>>(mask, aw1, ab1, aw2, ab2, aw3, ab3, aEmbB);
    node_features<<<dim3(1024), dim3(256), 0, stream>>>(mesh, midx, emb, pw1, pb1, pw2, pb2,
                                                        pw3, pb3, aEmbB, X0);
    // layer 0
    gemm_bt<0><<<dim3(512, 1), dim3(256), 0, stream>>>(X0, gw0T, 320, X1, FT, nullptr, nullptr);
    gemm_bt<2><<<dim3(32, 6), dim3(256), 0, stream>>>(adjB, FT, 4096, X1, nullptr, nullptr, gb0);
    // layer 1
    gemm_bt<0><<<dim3(512, 1), dim3(256), 0, stream>>>(X1, gw1T, 128, X2, FT, nullptr, nullptr);
    gemm_bt<2><<<dim3(32, 6), dim3(256), 0, stream>>>(adjB, FT, 4096, X2, nullptr, nullptr, gb1);
    // layer 2
    gemm_bt<0><<<dim3(512, 1), dim3(256), 0, stream>>>(X2, gw2T, 128, X1, FT, nullptr, nullptr);
    gemm_bt<2><<<dim3(32, 6), dim3(256), 0, stream>>>(adjB, FT, 4096, X1, nullptr, nullptr, gb2);
    // layer 3
    gemm_bt<1><<<dim3(512, 1), dim3(256), 0, stream>>>(X1, gw3T, 128, nullptr, FT, nullptr, nullptr);
    gemm_bt<3><<<dim3(32, 7), dim3(256), 0, stream>>>(adjB, FT, 4096, nullptr, nullptr, AGG3, gb3);

    max_reduce<<<dim3(800), dim3(256), 0, stream>>>(AGG3, out);
}